// Round 1
// baseline (483.350 us; speedup 1.0000x reference)
//
#include <hip/hip_runtime.h>
#include <hip/hip_bf16.h>

typedef __hip_bfloat16 bf16;
typedef __attribute__((ext_vector_type(8))) __bf16 bf16x8;
typedef __attribute__((ext_vector_type(4))) float f32x4;

constexpr int S_LEN = 2048;
constexpr int HID   = 2560;
constexpr int NH    = 40;
constexpr int QL    = 768;
constexpr int KVL   = 256;
constexpr int RD    = 32;
constexpr int ND    = 64;
constexpr int VD    = 64;
constexpr int QHD   = 96;                 // NOPE_D + ROPE_D
constexpr int QB_N  = NH * QHD;           // 3840
constexpr int KVB_N = NH * (ND + VD);     // 5120
constexpr int CKV_N = KVL + RD;           // 288

#define MFMA16(a, b, c) __builtin_amdgcn_mfma_f32_16x16x32_bf16((a), (b), (c), 0, 0, 0)

// position_ids may arrive as int32 or int64; values are 0..2047 so sniff layout.
__device__ __forceinline__ int get_pos(const int* pos, int s) {
  bool is64 = (pos[1] == 0 && pos[2] == 1);
  return is64 ? pos[2 * s] : pos[s];
}

// ---------------- prep ----------------

__global__ void cast_f32_bf16(const float* __restrict__ src, bf16* __restrict__ dst, int n4) {
  int i = blockIdx.x * blockDim.x + threadIdx.x;
  if (i >= n4) return;
  float4 v = reinterpret_cast<const float4*>(src)[i];
  struct { bf16 a, b, c, d; } pk;
  pk.a = __float2bfloat16(v.x); pk.b = __float2bfloat16(v.y);
  pk.c = __float2bfloat16(v.z); pk.d = __float2bfloat16(v.w);
  reinterpret_cast<uint2*>(dst)[i] = *reinterpret_cast<uint2*>(&pk);
}

// src [K][N] f32 -> dst [N][K] bf16  (B^T layout for the GEMMs)
__global__ void transpose_cast(const float* __restrict__ src, bf16* __restrict__ dst, int K, int N) {
  __shared__ float tile[32][33];
  int nb = blockIdx.x * 32, kb = blockIdx.y * 32;
  int x = threadIdx.x, y = threadIdx.y; // (32,8)
#pragma unroll
  for (int j = 0; j < 4; ++j) {
    int k = kb + y + j * 8, n = nb + x;
    tile[y + j * 8][x] = (k < K && n < N) ? src[(size_t)k * N + n] : 0.f;
  }
  __syncthreads();
#pragma unroll
  for (int j = 0; j < 4; ++j) {
    int n = nb + y + j * 8, k = kb + x;
    if (n < N && k < K) dst[(size_t)n * K + k] = __float2bfloat16(tile[x][y + j * 8]);
  }
}

// ---------------- GEMM: C[M][N] = A[M][K] * B^T[N][K], bf16 in, f32 acc ----------------

template<bool OBF16, bool NEDGE>
__global__ __launch_bounds__(256) void gemm_bt(const bf16* __restrict__ A,
                                               const bf16* __restrict__ B,
                                               void* __restrict__ Cv,
                                               int M, int N, int K) {
  constexpr int BM = 128, BN = 128, BK = 64;
  __shared__ __bf16 ldsA[BM * BK];
  __shared__ __bf16 ldsB[BN * BK];
  const int t = threadIdx.x;
  const int l = t & 63, w = t >> 6;
  const int lr = l & 15, lk = l >> 4;
  const int wr = w >> 1, wc = w & 1;
  const int rowbase = blockIdx.y * BM;
  const int colbase = blockIdx.x * BN;

  f32x4 acc[4][4];
#pragma unroll
  for (int m = 0; m < 4; ++m)
#pragma unroll
    for (int n = 0; n < 4; ++n) acc[m][n] = f32x4{0.f, 0.f, 0.f, 0.f};

  const int kiters = K / BK;
  for (int kt = 0; kt < kiters; ++kt) {
    const int kb = kt * BK;
    // stage A,B tiles: linear LDS dest, inverse-swizzled global source (rule #21)
#pragma unroll
    for (int it = 0; it < 4; ++it) {
      const int r  = it * 32 + w * 8 + (l >> 3);
      const int c8 = ((l & 7) * 8) ^ ((r & 7) << 3); // element-units, 16B chunks
      const bf16* ga = A + (size_t)(rowbase + r) * K + kb + c8;
      __builtin_amdgcn_global_load_lds((const __attribute__((address_space(1))) void*)ga,
          (__attribute__((address_space(3))) void*)(ldsA + it * 2048 + w * 512), 16, 0, 0);
      int nrow = colbase + r;
      if (NEDGE) nrow = (nrow < N) ? nrow : (N - 1);
      const bf16* gb = B + (size_t)nrow * K + kb + c8;
      __builtin_amdgcn_global_load_lds((const __attribute__((address_space(1))) void*)gb,
          (__attribute__((address_space(3))) void*)(ldsB + it * 2048 + w * 512), 16, 0, 0);
    }
    __syncthreads();
#pragma unroll
    for (int kk = 0; kk < 2; ++kk) {
      bf16x8 af[4], bfr[4];
#pragma unroll
      for (int m = 0; m < 4; ++m) {
        const int row = wr * 64 + m * 16 + lr;
        const int ce  = (kk * 32 + lk * 8) ^ ((row & 7) << 3);
        af[m] = *(const bf16x8*)(ldsA + row * BK + ce);
      }
#pragma unroll
      for (int n = 0; n < 4; ++n) {
        const int row = wc * 64 + n * 16 + lr;
        const int ce  = (kk * 32 + lk * 8) ^ ((row & 7) << 3);
        bfr[n] = *(const bf16x8*)(ldsB + row * BK + ce);
      }
#pragma unroll
      for (int m = 0; m < 4; ++m)
#pragma unroll
        for (int n = 0; n < 4; ++n)
          acc[m][n] = MFMA16(af[m], bfr[n], acc[m][n]);
    }
    __syncthreads();
  }

  // epilogue: C row=(lk*4+i), col=lr within each 16x16 frag
#pragma unroll
  for (int m = 0; m < 4; ++m)
#pragma unroll
    for (int n = 0; n < 4; ++n) {
      const int col = colbase + wc * 64 + n * 16 + lr;
      if (NEDGE && col >= N) continue;
#pragma unroll
      for (int i = 0; i < 4; ++i) {
        const int row = rowbase + wr * 64 + m * 16 + lk * 4 + i;
        if (OBF16) ((bf16*)Cv)[(size_t)row * N + col] = __float2bfloat16(acc[m][n][i]);
        else       ((float*)Cv)[(size_t)row * N + col] = acc[m][n][i];
      }
    }
}

// ---------------- norms / rope / reshapes ----------------

__global__ void rmsnorm_rows(const float* __restrict__ in, const float* __restrict__ w,
                             bf16* __restrict__ out, int C) {
  const int r = blockIdx.x;
  const float* row = in + (size_t)r * C;
  float ss = 0.f;
  for (int c = threadIdx.x; c < C; c += 256) { float v = row[c]; ss += v * v; }
#pragma unroll
  for (int d = 32; d > 0; d >>= 1) ss += __shfl_xor(ss, d);
  __shared__ float red[4];
  if ((threadIdx.x & 63) == 0) red[threadIdx.x >> 6] = ss;
  __syncthreads();
  const float tot = red[0] + red[1] + red[2] + red[3];
  const float rs = rsqrtf(tot / (float)C + 1e-6f);
  for (int c = threadIdx.x; c < C; c += 256)
    out[(size_t)r * C + c] = __float2bfloat16(row[c] * rs * w[c]);
}

// per row: rmsnorm(ckv[0:256]) -> bf16 ; rope(k_pe = ckv[256:288]) -> bf16
__global__ void kv_prep(const float* __restrict__ ckv, const float* __restrict__ w,
                        const int* __restrict__ pos, bf16* __restrict__ ckv_bf,
                        bf16* __restrict__ kpe) {
  const int s = blockIdx.x, t = threadIdx.x; // 64 threads
  const float* row = ckv + (size_t)s * CKV_N;
  float v[4]; float ss = 0.f;
#pragma unroll
  for (int j = 0; j < 4; ++j) { v[j] = row[t + 64 * j]; ss += v[j] * v[j]; }
#pragma unroll
  for (int d = 32; d > 0; d >>= 1) ss += __shfl_xor(ss, d);
  const float rs = rsqrtf(ss / (float)KVL + 1e-6f);
#pragma unroll
  for (int j = 0; j < 4; ++j)
    ckv_bf[(size_t)s * KVL + t + 64 * j] = __float2bfloat16(v[j] * rs * w[t + 64 * j]);
  if (t < 16) {
    const float x0 = row[KVL + t], x1 = row[KVL + 16 + t];
    const float p = (float)get_pos(pos, s);
    const float invf = exp2f(-(float)t * (13.2877124f / 16.f)); // 10000^(-t/16)
    const float ang = p * invf, c = cosf(ang), sn = sinf(ang);
    kpe[(size_t)s * RD + t]      = __float2bfloat16(x0 * c - x1 * sn);
    kpe[(size_t)s * RD + 16 + t] = __float2bfloat16(x1 * c + x0 * sn);
  }
}

// qraw [S][3840] -> qfull [NH][S][96], rope on last 32, *96^-0.5
__global__ void rope_q(const bf16* __restrict__ qraw, const int* __restrict__ pos,
                       bf16* __restrict__ qfull) {
  const int s = blockIdx.x, h = blockIdx.y, d = threadIdx.x; // 96 threads
  const float scale = 0.1020620726f;
  const size_t src = (size_t)s * QB_N + h * QHD;
  float outv;
  if (d < ND) {
    outv = __bfloat162float(qraw[src + d]);
  } else {
    const int j = (d - ND) & 15;
    const float x0 = __bfloat162float(qraw[src + ND + j]);
    const float x1 = __bfloat162float(qraw[src + ND + 16 + j]);
    const float p = (float)get_pos(pos, s);
    const float invf = exp2f(-(float)j * (13.2877124f / 16.f));
    const float ang = p * invf, c = cosf(ang), sn = sinf(ang);
    outv = (d < ND + 16) ? (x0 * c - x1 * sn) : (x1 * c + x0 * sn);
  }
  qfull[((size_t)h * S_LEN + s) * QHD + d] = __float2bfloat16(outv * scale);
}

__global__ void build_kfull(const bf16* __restrict__ kv, const bf16* __restrict__ kpe,
                            bf16* __restrict__ kfull) {
  const int s = blockIdx.x, h = blockIdx.y, d = threadIdx.x; // 96 threads
  bf16 v = (d < ND) ? kv[(size_t)s * KVB_N + h * (ND + VD) + d]
                    : kpe[(size_t)s * RD + (d - ND)];
  kfull[((size_t)h * S_LEN + s) * QHD + d] = v;
}

// V part of kv [S][5120] -> vt [NH][64][S]
__global__ void transpose_v(const bf16* __restrict__ kv, bf16* __restrict__ vt) {
  __shared__ bf16 tile[32][33];
  const int h = blockIdx.z;
  const int sb = blockIdx.x * 32, db = blockIdx.y * 32;
  const int x = threadIdx.x, y = threadIdx.y; // (32,8)
#pragma unroll
  for (int j = 0; j < 4; ++j)
    tile[y + j * 8][x] = kv[(size_t)(sb + y + j * 8) * KVB_N + h * (ND + VD) + ND + db + x];
  __syncthreads();
#pragma unroll
  for (int j = 0; j < 4; ++j)
    vt[((size_t)h * VD + db + y + j * 8) * S_LEN + sb + x] = tile[x][y + j * 8];
}

// ---------------- causal flash attention ----------------
// block = (head, 128 q rows), 4 waves x 32 rows, no inter-wave sync needed.
__global__ __launch_bounds__(256) void attn_kernel(const bf16* __restrict__ qfull,
                                                   const bf16* __restrict__ kfull,
                                                   const bf16* __restrict__ vt,
                                                   bf16* __restrict__ ctx) {
  const int h = blockIdx.y;
  const int qb = blockIdx.x * 128;
  const int t = threadIdx.x, l = t & 63, w = t >> 6;
  const int lr = l & 15, lk = l >> 4;
  const int qw = qb + w * 32;
  const bf16* Q  = qfull + (size_t)h * S_LEN * QHD;
  const bf16* Kf = kfull + (size_t)h * S_LEN * QHD;
  const bf16* V  = vt + (size_t)h * VD * S_LEN;
  __shared__ __bf16 plds[4][32][40]; // per-wave P tile, stride 40 to spread banks

  bf16x8 qf[2][3];
#pragma unroll
  for (int qg = 0; qg < 2; ++qg)
#pragma unroll
    for (int ks = 0; ks < 3; ++ks)
      qf[qg][ks] = *(const bf16x8*)(Q + (size_t)(qw + qg * 16 + lr) * QHD + ks * 32 + lk * 8);

  f32x4 o[2][4];
  float mrow[2][4], lrow[2][4];
#pragma unroll
  for (int qg = 0; qg < 2; ++qg) {
#pragma unroll
    for (int dt = 0; dt < 4; ++dt) o[qg][dt] = f32x4{0.f, 0.f, 0.f, 0.f};
#pragma unroll
    for (int i = 0; i < 4; ++i) { mrow[qg][i] = -1e30f; lrow[qg][i] = 0.f; }
  }

  for (int kb = 0; kb <= qw; kb += 32) {
    f32x4 sfr[2][2];
#pragma unroll
    for (int qg = 0; qg < 2; ++qg)
#pragma unroll
      for (int sub = 0; sub < 2; ++sub) sfr[qg][sub] = f32x4{0.f, 0.f, 0.f, 0.f};

    bf16x8 kf[2][3];
#pragma unroll
    for (int sub = 0; sub < 2; ++sub)
#pragma unroll
      for (int ks = 0; ks < 3; ++ks)
        kf[sub][ks] = *(const bf16x8*)(Kf + (size_t)(kb + sub * 16 + lr) * QHD + ks * 32 + lk * 8);
#pragma unroll
    for (int qg = 0; qg < 2; ++qg)
#pragma unroll
      for (int sub = 0; sub < 2; ++sub)
#pragma unroll
        for (int ks = 0; ks < 3; ++ks)
          sfr[qg][sub] = MFMA16(qf[qg][ks], kf[sub][ks], sfr[qg][sub]);

    const bool diag = (kb == qw);
#pragma unroll
    for (int qg = 0; qg < 2; ++qg) {
      float fac[4];
#pragma unroll
      for (int i = 0; i < 4; ++i) {
        const int qrow = qg * 16 + lk * 4 + i; // local q row (0..31)
        if (diag) {
#pragma unroll
          for (int sub = 0; sub < 2; ++sub)
            if (kb + sub * 16 + lr > qw + qrow) sfr[qg][sub][i] = -1e30f;
        }
        float tm = fmaxf(sfr[qg][0][i], sfr[qg][1][i]);
        tm = fmaxf(tm, __shfl_xor(tm, 1));
        tm = fmaxf(tm, __shfl_xor(tm, 2));
        tm = fmaxf(tm, __shfl_xor(tm, 4));
        tm = fmaxf(tm, __shfl_xor(tm, 8));
        const float mnew = fmaxf(mrow[qg][i], tm);
        const float f = __expf(mrow[qg][i] - mnew);
        mrow[qg][i] = mnew;
        const float p0 = __expf(sfr[qg][0][i] - mnew);
        const float p1 = __expf(sfr[qg][1][i] - mnew);
        float ts = p0 + p1;
        ts += __shfl_xor(ts, 1);
        ts += __shfl_xor(ts, 2);
        ts += __shfl_xor(ts, 4);
        ts += __shfl_xor(ts, 8);
        lrow[qg][i] = lrow[qg][i] * f + ts;
        fac[i] = f;
        plds[w][qrow][lr]      = (__bf16)p0;
        plds[w][qrow][16 + lr] = (__bf16)p1;
      }
#pragma unroll
      for (int dt = 0; dt < 4; ++dt)
#pragma unroll
        for (int i = 0; i < 4; ++i) o[qg][dt][i] *= fac[i];
    }
    // PV: A = P from LDS (A-frag layout), B = V^T rows (contiguous in s)
    bf16x8 pa0 = *(const bf16x8*)(&plds[w][lr][lk * 8]);
    bf16x8 pa1 = *(const bf16x8*)(&plds[w][16 + lr][lk * 8]);
#pragma unroll
    for (int dt = 0; dt < 4; ++dt) {
      bf16x8 vf = *(const bf16x8*)(V + (size_t)(dt * 16 + lr) * S_LEN + kb + lk * 8);
      o[0][dt] = MFMA16(pa0, vf, o[0][dt]);
      o[1][dt] = MFMA16(pa1, vf, o[1][dt]);
    }
  }

#pragma unroll
  for (int qg = 0; qg < 2; ++qg) {
    float inv[4];
#pragma unroll
    for (int i = 0; i < 4; ++i) inv[i] = 1.0f / lrow[qg][i];
#pragma unroll
    for (int dt = 0; dt < 4; ++dt)
#pragma unroll
      for (int i = 0; i < 4; ++i) {
        const int row = qw + qg * 16 + lk * 4 + i;
        const int col = h * VD + dt * 16 + lr;
        ctx[(size_t)row * HID + col] = __float2bfloat16(o[qg][dt][i] * inv[i]);
      }
  }
}

// ---------------- launch ----------------

extern "C" void kernel_launch(void* const* d_in, const int* in_sizes, int n_in,
                              void* d_out, int out_size, void* d_ws, size_t ws_size,
                              hipStream_t stream) {
  const float* hidden = (const float*)d_in[0];
  const int*   pos    = (const int*)d_in[1];
  const float* w_qa   = (const float*)d_in[2];
  const float* q_ln   = (const float*)d_in[3];
  const float* w_qb   = (const float*)d_in[4];
  const float* w_kva  = (const float*)d_in[5];
  const float* kv_ln  = (const float*)d_in[6];
  const float* w_kvb  = (const float*)d_in[7];
  const float* w_o    = (const float*)d_in[8];
  float* out = (float*)d_out;
  char* ws = (char*)d_ws;
  (void)in_sizes; (void)n_in; (void)out_size; (void)ws_size;

  size_t off = 0;
  auto take = [&](size_t bytes) -> char* {
    char* p = ws + off;
    off = (off + bytes + 255) & ~(size_t)255;
    return p;
  };
  bf16*  hid_bf = (bf16*)take((size_t)S_LEN * HID * 2);
  bf16*  wqaT   = (bf16*)take((size_t)QL * HID * 2);
  bf16*  wqbT   = (bf16*)take((size_t)QB_N * QL * 2);
  bf16*  wkvaT  = (bf16*)take((size_t)CKV_N * HID * 2);
  bf16*  wkvbT  = (bf16*)take((size_t)KVB_N * KVL * 2);
  bf16*  woT    = (bf16*)take((size_t)HID * HID * 2);
  float* qlora  = (float*)take((size_t)S_LEN * QL * 4);
  bf16*  qa_bf  = (bf16*)take((size_t)S_LEN * QL * 2);
  bf16*  qraw   = (bf16*)take((size_t)S_LEN * QB_N * 2);
  bf16*  qfull  = (bf16*)take((size_t)NH * S_LEN * QHD * 2);
  float* ckv    = (float*)take((size_t)S_LEN * CKV_N * 4);
  bf16*  ckv_bf = (bf16*)take((size_t)S_LEN * KVL * 2);
  bf16*  kpe    = (bf16*)take((size_t)S_LEN * RD * 2);
  bf16*  kv_bf  = (bf16*)take((size_t)S_LEN * KVB_N * 2);
  bf16*  kfull  = (bf16*)take((size_t)NH * S_LEN * QHD * 2);
  bf16*  vt     = (bf16*)take((size_t)NH * VD * S_LEN * 2);
  bf16*  ctx    = (bf16*)take((size_t)S_LEN * HID * 2);

  const dim3 tb(32, 8);
  cast_f32_bf16<<<(S_LEN * HID / 4 + 255) / 256, 256, 0, stream>>>(hidden, hid_bf, S_LEN * HID / 4);
  transpose_cast<<<dim3((QL + 31) / 32, (HID + 31) / 32), tb, 0, stream>>>(w_qa, wqaT, HID, QL);
  transpose_cast<<<dim3((QB_N + 31) / 32, (QL + 31) / 32), tb, 0, stream>>>(w_qb, wqbT, QL, QB_N);
  transpose_cast<<<dim3((CKV_N + 31) / 32, (HID + 31) / 32), tb, 0, stream>>>(w_kva, wkvaT, HID, CKV_N);
  transpose_cast<<<dim3((KVB_N + 31) / 32, (KVL + 31) / 32), tb, 0, stream>>>(w_kvb, wkvbT, KVL, KVB_N);
  transpose_cast<<<dim3((HID + 31) / 32, (HID + 31) / 32), tb, 0, stream>>>(w_o, woT, HID, HID);

  // q path
  gemm_bt<false, false><<<dim3(QL / 128, S_LEN / 128), 256, 0, stream>>>(hid_bf, wqaT, qlora, S_LEN, QL, HID);
  rmsnorm_rows<<<S_LEN, 256, 0, stream>>>(qlora, q_ln, qa_bf, QL);
  gemm_bt<true, false><<<dim3(QB_N / 128, S_LEN / 128), 256, 0, stream>>>(qa_bf, wqbT, qraw, S_LEN, QB_N, QL);
  rope_q<<<dim3(S_LEN, NH), 96, 0, stream>>>(qraw, pos, qfull);

  // kv path
  gemm_bt<false, true><<<dim3((CKV_N + 127) / 128, S_LEN / 128), 256, 0, stream>>>(hid_bf, wkvaT, ckv, S_LEN, CKV_N, HID);
  kv_prep<<<S_LEN, 64, 0, stream>>>(ckv, kv_ln, pos, ckv_bf, kpe);
  gemm_bt<true, false><<<dim3(KVB_N / 128, S_LEN / 128), 256, 0, stream>>>(ckv_bf, wkvbT, kv_bf, S_LEN, KVB_N, KVL);
  build_kfull<<<dim3(S_LEN, NH), 96, 0, stream>>>(kv_bf, kpe, kfull);
  transpose_v<<<dim3(S_LEN / 32, VD / 32, NH), tb, 0, stream>>>(kv_bf, vt);

  // attention + output proj
  attn_kernel<<<dim3(S_LEN / 128, NH), 256, 0, stream>>>(qfull, kfull, vt, ctx);
  gemm_bt<false, false><<<dim3(HID / 128, S_LEN / 128), 256, 0, stream>>>(ctx, woT, out, S_LEN, HID, HID);
}

// Round 2
// 425.109 us; speedup vs baseline: 1.1370x; 1.1370x over previous
//
#include <hip/hip_runtime.h>
#include <hip/hip_bf16.h>

typedef __hip_bfloat16 bf16;
typedef __attribute__((ext_vector_type(8))) __bf16 bf16x8;
typedef __attribute__((ext_vector_type(4))) float f32x4;

constexpr int S_LEN = 2048;
constexpr int HID   = 2560;
constexpr int NH    = 40;
constexpr int QL    = 768;
constexpr int KVL   = 256;
constexpr int RD    = 32;
constexpr int ND    = 64;
constexpr int VD    = 64;
constexpr int QHD   = 96;                 // NOPE_D + ROPE_D
constexpr int QB_N  = NH * QHD;           // 3840
constexpr int KVB_N = NH * (ND + VD);     // 5120
constexpr int CKV_N = KVL + RD;           // 288

#define MFMA16(a, b, c) __builtin_amdgcn_mfma_f32_16x16x32_bf16((a), (b), (c), 0, 0, 0)

// position_ids may arrive as int32 or int64; values are 0..2047 so sniff layout.
__device__ __forceinline__ int get_pos(const int* pos, int s) {
  bool is64 = (pos[1] == 0 && pos[2] == 1);
  return is64 ? pos[2 * s] : pos[s];
}

// ---------------- prep ----------------

__global__ void cast_f32_bf16(const float* __restrict__ src, bf16* __restrict__ dst, int n4) {
  int i = blockIdx.x * blockDim.x + threadIdx.x;
  if (i >= n4) return;
  float4 v = reinterpret_cast<const float4*>(src)[i];
  struct { bf16 a, b, c, d; } pk;
  pk.a = __float2bfloat16(v.x); pk.b = __float2bfloat16(v.y);
  pk.c = __float2bfloat16(v.z); pk.d = __float2bfloat16(v.w);
  reinterpret_cast<uint2*>(dst)[i] = *reinterpret_cast<uint2*>(&pk);
}

// src [K][N] f32 -> dst [N][K] bf16  (B^T layout for the GEMMs)
__global__ void transpose_cast(const float* __restrict__ src, bf16* __restrict__ dst, int K, int N) {
  __shared__ float tile[32][33];
  int nb = blockIdx.x * 32, kb = blockIdx.y * 32;
  int x = threadIdx.x, y = threadIdx.y; // (32,8)
#pragma unroll
  for (int j = 0; j < 4; ++j) {
    int k = kb + y + j * 8, n = nb + x;
    tile[y + j * 8][x] = (k < K && n < N) ? src[(size_t)k * N + n] : 0.f;
  }
  __syncthreads();
#pragma unroll
  for (int j = 0; j < 4; ++j) {
    int n = nb + y + j * 8, k = kb + x;
    if (n < N && k < K) dst[(size_t)n * K + k] = __float2bfloat16(tile[x][y + j * 8]);
  }
}

// ---------------- GEMM: C[M][N] = A[M][K] * B^T[N][K], bf16 in, f32 acc ----------------

template<bool OBF16, bool NEDGE>
__global__ __launch_bounds__(256) void gemm_bt(const bf16* __restrict__ A,
                                               const bf16* __restrict__ B,
                                               void* __restrict__ Cv,
                                               int M, int N, int K) {
  constexpr int BM = 128, BN = 128, BK = 64;
  __shared__ __bf16 ldsA[BM * BK];
  __shared__ __bf16 ldsB[BN * BK];
  const int t = threadIdx.x;
  const int l = t & 63, w = t >> 6;
  const int lr = l & 15, lk = l >> 4;
  const int wr = w >> 1, wc = w & 1;
  const int rowbase = blockIdx.y * BM;
  const int colbase = blockIdx.x * BN;

  f32x4 acc[4][4];
#pragma unroll
  for (int m = 0; m < 4; ++m)
#pragma unroll
    for (int n = 0; n < 4; ++n) acc[m][n] = f32x4{0.f, 0.f, 0.f, 0.f};

  const int kiters = K / BK;
  for (int kt = 0; kt < kiters; ++kt) {
    const int kb = kt * BK;
    // stage A,B tiles: linear LDS dest, inverse-swizzled global source (rule #21)
#pragma unroll
    for (int it = 0; it < 4; ++it) {
      const int r  = it * 32 + w * 8 + (l >> 3);
      const int c8 = ((l & 7) * 8) ^ ((r & 7) << 3); // element-units, 16B chunks
      const bf16* ga = A + (size_t)(rowbase + r) * K + kb + c8;
      __builtin_amdgcn_global_load_lds((const __attribute__((address_space(1))) void*)ga,
          (__attribute__((address_space(3))) void*)(ldsA + it * 2048 + w * 512), 16, 0, 0);
      int nrow = colbase + r;
      if (NEDGE) nrow = (nrow < N) ? nrow : (N - 1);
      const bf16* gb = B + (size_t)nrow * K + kb + c8;
      __builtin_amdgcn_global_load_lds((const __attribute__((address_space(1))) void*)gb,
          (__attribute__((address_space(3))) void*)(ldsB + it * 2048 + w * 512), 16, 0, 0);
    }
    __syncthreads();
#pragma unroll
    for (int kk = 0; kk < 2; ++kk) {
      bf16x8 af[4], bfr[4];
#pragma unroll
      for (int m = 0; m < 4; ++m) {
        const int row = wr * 64 + m * 16 + lr;
        const int ce  = (kk * 32 + lk * 8) ^ ((row & 7) << 3);
        af[m] = *(const bf16x8*)(ldsA + row * BK + ce);
      }
#pragma unroll
      for (int n = 0; n < 4; ++n) {
        const int row = wc * 64 + n * 16 + lr;
        const int ce  = (kk * 32 + lk * 8) ^ ((row & 7) << 3);
        bfr[n] = *(const bf16x8*)(ldsB + row * BK + ce);
      }
#pragma unroll
      for (int m = 0; m < 4; ++m)
#pragma unroll
        for (int n = 0; n < 4; ++n)
          acc[m][n] = MFMA16(af[m], bfr[n], acc[m][n]);
    }
    __syncthreads();
  }

  // epilogue: C row=(lk*4+i), col=lr within each 16x16 frag
#pragma unroll
  for (int m = 0; m < 4; ++m)
#pragma unroll
    for (int n = 0; n < 4; ++n) {
      const int col = colbase + wc * 64 + n * 16 + lr;
      if (NEDGE && col >= N) continue;
#pragma unroll
      for (int i = 0; i < 4; ++i) {
        const int row = rowbase + wr * 64 + m * 16 + lk * 4 + i;
        if (OBF16) ((bf16*)Cv)[(size_t)row * N + col] = __float2bfloat16(acc[m][n][i]);
        else       ((float*)Cv)[(size_t)row * N + col] = acc[m][n][i];
      }
    }
}

// ---------------- norms / rope / reshapes ----------------

__global__ void rmsnorm_rows(const float* __restrict__ in, const float* __restrict__ w,
                             bf16* __restrict__ out, int C) {
  const int r = blockIdx.x;
  const float* row = in + (size_t)r * C;
  float ss = 0.f;
  for (int c = threadIdx.x; c < C; c += 256) { float v = row[c]; ss += v * v; }
#pragma unroll
  for (int d = 32; d > 0; d >>= 1) ss += __shfl_xor(ss, d);
  __shared__ float red[4];
  if ((threadIdx.x & 63) == 0) red[threadIdx.x >> 6] = ss;
  __syncthreads();
  const float tot = red[0] + red[1] + red[2] + red[3];
  const float rs = rsqrtf(tot / (float)C + 1e-6f);
  for (int c = threadIdx.x; c < C; c += 256)
    out[(size_t)r * C + c] = __float2bfloat16(row[c] * rs * w[c]);
}

// per row: rmsnorm(ckv[0:256]) -> bf16 ; rope(k_pe = ckv[256:288]) -> bf16
__global__ void kv_prep(const float* __restrict__ ckv, const float* __restrict__ w,
                        const int* __restrict__ pos, bf16* __restrict__ ckv_bf,
                        bf16* __restrict__ kpe) {
  const int s = blockIdx.x, t = threadIdx.x; // 64 threads
  const float* row = ckv + (size_t)s * CKV_N;
  float v[4]; float ss = 0.f;
#pragma unroll
  for (int j = 0; j < 4; ++j) { v[j] = row[t + 64 * j]; ss += v[j] * v[j]; }
#pragma unroll
  for (int d = 32; d > 0; d >>= 1) ss += __shfl_xor(ss, d);
  const float rs = rsqrtf(ss / (float)KVL + 1e-6f);
#pragma unroll
  for (int j = 0; j < 4; ++j)
    ckv_bf[(size_t)s * KVL + t + 64 * j] = __float2bfloat16(v[j] * rs * w[t + 64 * j]);
  if (t < 16) {
    const float x0 = row[KVL + t], x1 = row[KVL + 16 + t];
    const float p = (float)get_pos(pos, s);
    const float invf = exp2f(-(float)t * (13.2877124f / 16.f)); // 10000^(-t/16)
    const float ang = p * invf, c = cosf(ang), sn = sinf(ang);
    kpe[(size_t)s * RD + t]      = __float2bfloat16(x0 * c - x1 * sn);
    kpe[(size_t)s * RD + 16 + t] = __float2bfloat16(x1 * c + x0 * sn);
  }
}

// qraw [S][3840] -> qfull [NH][S][96], rope on last 32, *96^-0.5
__global__ void rope_q(const bf16* __restrict__ qraw, const int* __restrict__ pos,
                       bf16* __restrict__ qfull) {
  const int s = blockIdx.x, h = blockIdx.y, d = threadIdx.x; // 96 threads
  const float scale = 0.1020620726f;
  const size_t src = (size_t)s * QB_N + h * QHD;
  float outv;
  if (d < ND) {
    outv = __bfloat162float(qraw[src + d]);
  } else {
    const int j = (d - ND) & 15;
    const float x0 = __bfloat162float(qraw[src + ND + j]);
    const float x1 = __bfloat162float(qraw[src + ND + 16 + j]);
    const float p = (float)get_pos(pos, s);
    const float invf = exp2f(-(float)j * (13.2877124f / 16.f));
    const float ang = p * invf, c = cosf(ang), sn = sinf(ang);
    outv = (d < ND + 16) ? (x0 * c - x1 * sn) : (x1 * c + x0 * sn);
  }
  qfull[((size_t)h * S_LEN + s) * QHD + d] = __float2bfloat16(outv * scale);
}

__global__ void build_kfull(const bf16* __restrict__ kv, const bf16* __restrict__ kpe,
                            bf16* __restrict__ kfull) {
  const int s = blockIdx.x, h = blockIdx.y, d = threadIdx.x; // 96 threads
  bf16 v = (d < ND) ? kv[(size_t)s * KVB_N + h * (ND + VD) + d]
                    : kpe[(size_t)s * RD + (d - ND)];
  kfull[((size_t)h * S_LEN + s) * QHD + d] = v;
}

// V part of kv [S][5120] -> vt [NH][64][S]
__global__ void transpose_v(const bf16* __restrict__ kv, bf16* __restrict__ vt) {
  __shared__ bf16 tile[32][33];
  const int h = blockIdx.z;
  const int sb = blockIdx.x * 32, db = blockIdx.y * 32;
  const int x = threadIdx.x, y = threadIdx.y; // (32,8)
#pragma unroll
  for (int j = 0; j < 4; ++j)
    tile[y + j * 8][x] = kv[(size_t)(sb + y + j * 8) * KVB_N + h * (ND + VD) + ND + db + x];
  __syncthreads();
#pragma unroll
  for (int j = 0; j < 4; ++j)
    vt[((size_t)h * VD + db + y + j * 8) * S_LEN + sb + x] = tile[x][y + j * 8];
}

// ---------------- causal flash attention ----------------
// One wave (64 threads) per block, 32 q-rows, KVBLK=64, K prefetch.
// Grid (NH, S/32) with q-tiles REVERSED (heavy blocks dispatch first -> LPT).
__global__ __launch_bounds__(64) void attn_kernel(const bf16* __restrict__ qfull,
                                                  const bf16* __restrict__ kfull,
                                                  const bf16* __restrict__ vt,
                                                  bf16* __restrict__ ctx) {
  const int h = blockIdx.x;
  const int qw = ((int)gridDim.y - 1 - (int)blockIdx.y) * 32;
  const int l = threadIdx.x;
  const int lr = l & 15, lk = l >> 4;
  const bf16* Q  = qfull + (size_t)h * S_LEN * QHD;
  const bf16* Kf = kfull + (size_t)h * S_LEN * QHD;
  const bf16* V  = vt + (size_t)h * VD * S_LEN;
  __shared__ __bf16 plds[32][72]; // 144B row stride: uniform bank spread on b128 reads

  bf16x8 qf[2][3];
#pragma unroll
  for (int qg = 0; qg < 2; ++qg)
#pragma unroll
    for (int ks = 0; ks < 3; ++ks)
      qf[qg][ks] = *(const bf16x8*)(Q + (size_t)(qw + qg * 16 + lr) * QHD + ks * 32 + lk * 8);

  f32x4 o[2][4];
  float mrow[2][4], lrow[2][4];
#pragma unroll
  for (int qg = 0; qg < 2; ++qg) {
#pragma unroll
    for (int dt = 0; dt < 4; ++dt) o[qg][dt] = f32x4{0.f, 0.f, 0.f, 0.f};
#pragma unroll
    for (int i = 0; i < 4; ++i) { mrow[qg][i] = -1e30f; lrow[qg][i] = 0.f; }
  }

  // preload K tile 0
  bf16x8 kf[4][3];
#pragma unroll
  for (int sub = 0; sub < 4; ++sub)
#pragma unroll
    for (int ks = 0; ks < 3; ++ks)
      kf[sub][ks] = *(const bf16x8*)(Kf + (size_t)(sub * 16 + lr) * QHD + ks * 32 + lk * 8);

  for (int kb = 0;; kb += 64) {
    // QK^T: 32 rows x 64 cols
    f32x4 sfr[2][4];
#pragma unroll
    for (int qg = 0; qg < 2; ++qg)
#pragma unroll
      for (int sub = 0; sub < 4; ++sub) sfr[qg][sub] = f32x4{0.f, 0.f, 0.f, 0.f};
#pragma unroll
    for (int qg = 0; qg < 2; ++qg)
#pragma unroll
      for (int sub = 0; sub < 4; ++sub)
#pragma unroll
        for (int ks = 0; ks < 3; ++ks)
          sfr[qg][sub] = MFMA16(qf[qg][ks], kf[sub][ks], sfr[qg][sub]);

    // prefetch next K tile (hidden under softmax+PV)
    const int nkb = kb + 64;
    if (nkb <= qw) {
#pragma unroll
      for (int sub = 0; sub < 4; ++sub)
#pragma unroll
        for (int ks = 0; ks < 3; ++ks)
          kf[sub][ks] = *(const bf16x8*)(Kf + (size_t)(nkb + sub * 16 + lr) * QHD + ks * 32 + lk * 8);
    }

    const bool diag = (kb + 64 > qw);
#pragma unroll
    for (int qg = 0; qg < 2; ++qg) {
      float fac[4];
#pragma unroll
      for (int i = 0; i < 4; ++i) {
        const int qrow = qg * 16 + lk * 4 + i; // local q row (0..31)
        if (diag) {
#pragma unroll
          for (int sub = 0; sub < 4; ++sub)
            if (kb + sub * 16 + lr > qw + qrow) sfr[qg][sub][i] = -1e30f;
        }
        float tm = fmaxf(fmaxf(sfr[qg][0][i], sfr[qg][1][i]),
                         fmaxf(sfr[qg][2][i], sfr[qg][3][i]));
        tm = fmaxf(tm, __shfl_xor(tm, 1));
        tm = fmaxf(tm, __shfl_xor(tm, 2));
        tm = fmaxf(tm, __shfl_xor(tm, 4));
        tm = fmaxf(tm, __shfl_xor(tm, 8));
        const float mnew = fmaxf(mrow[qg][i], tm);
        const float f = __expf(mrow[qg][i] - mnew);
        mrow[qg][i] = mnew;
        float p[4];
#pragma unroll
        for (int sub = 0; sub < 4; ++sub) p[sub] = __expf(sfr[qg][sub][i] - mnew);
        float ts = (p[0] + p[1]) + (p[2] + p[3]);
        ts += __shfl_xor(ts, 1);
        ts += __shfl_xor(ts, 2);
        ts += __shfl_xor(ts, 4);
        ts += __shfl_xor(ts, 8);
        lrow[qg][i] = lrow[qg][i] * f + ts;
        fac[i] = f;
#pragma unroll
        for (int sub = 0; sub < 4; ++sub)
          plds[qrow][sub * 16 + lr] = (__bf16)p[sub];
      }
#pragma unroll
      for (int dt = 0; dt < 4; ++dt)
#pragma unroll
        for (int i = 0; i < 4; ++i) o[qg][dt][i] *= fac[i];
    }

    // PV: A = P from LDS (A-frag layout), B = V^T rows (contiguous in s)
#pragma unroll
    for (int h2 = 0; h2 < 2; ++h2) {
      bf16x8 pa0 = *(const bf16x8*)(&plds[lr][h2 * 32 + lk * 8]);
      bf16x8 pa1 = *(const bf16x8*)(&plds[16 + lr][h2 * 32 + lk * 8]);
#pragma unroll
      for (int dt = 0; dt < 4; ++dt) {
        bf16x8 vf = *(const bf16x8*)(V + (size_t)(dt * 16 + lr) * S_LEN + kb + h2 * 32 + lk * 8);
        o[0][dt] = MFMA16(pa0, vf, o[0][dt]);
        o[1][dt] = MFMA16(pa1, vf, o[1][dt]);
      }
    }
    if (nkb > qw) break;
  }

#pragma unroll
  for (int qg = 0; qg < 2; ++qg) {
    float inv[4];
#pragma unroll
    for (int i = 0; i < 4; ++i) inv[i] = 1.0f / lrow[qg][i];
#pragma unroll
    for (int dt = 0; dt < 4; ++dt)
#pragma unroll
      for (int i = 0; i < 4; ++i) {
        const int row = qw + qg * 16 + lk * 4 + i;
        const int col = h * VD + dt * 16 + lr;
        ctx[(size_t)row * HID + col] = __float2bfloat16(o[qg][dt][i] * inv[i]);
      }
  }
}

// ---------------- launch ----------------

extern "C" void kernel_launch(void* const* d_in, const int* in_sizes, int n_in,
                              void* d_out, int out_size, void* d_ws, size_t ws_size,
                              hipStream_t stream) {
  const float* hidden = (const float*)d_in[0];
  const int*   pos    = (const int*)d_in[1];
  const float* w_qa   = (const float*)d_in[2];
  const float* q_ln   = (const float*)d_in[3];
  const float* w_qb   = (const float*)d_in[4];
  const float* w_kva  = (const float*)d_in[5];
  const float* kv_ln  = (const float*)d_in[6];
  const float* w_kvb  = (const float*)d_in[7];
  const float* w_o    = (const float*)d_in[8];
  float* out = (float*)d_out;
  char* ws = (char*)d_ws;
  (void)in_sizes; (void)n_in; (void)out_size; (void)ws_size;

  size_t off = 0;
  auto take = [&](size_t bytes) -> char* {
    char* p = ws + off;
    off = (off + bytes + 255) & ~(size_t)255;
    return p;
  };
  bf16*  hid_bf = (bf16*)take((size_t)S_LEN * HID * 2);
  bf16*  wqaT   = (bf16*)take((size_t)QL * HID * 2);
  bf16*  wqbT   = (bf16*)take((size_t)QB_N * QL * 2);
  bf16*  wkvaT  = (bf16*)take((size_t)CKV_N * HID * 2);
  bf16*  wkvbT  = (bf16*)take((size_t)KVB_N * KVL * 2);
  bf16*  woT    = (bf16*)take((size_t)HID * HID * 2);
  float* qlora  = (float*)take((size_t)S_LEN * QL * 4);
  bf16*  qa_bf  = (bf16*)take((size_t)S_LEN * QL * 2);
  bf16*  qraw   = (bf16*)take((size_t)S_LEN * QB_N * 2);
  bf16*  qfull  = (bf16*)take((size_t)NH * S_LEN * QHD * 2);
  float* ckv    = (float*)take((size_t)S_LEN * CKV_N * 4);
  bf16*  ckv_bf = (bf16*)take((size_t)S_LEN * KVL * 2);
  bf16*  kpe    = (bf16*)take((size_t)S_LEN * RD * 2);
  bf16*  kv_bf  = (bf16*)take((size_t)S_LEN * KVB_N * 2);
  bf16*  kfull  = (bf16*)take((size_t)NH * S_LEN * QHD * 2);
  bf16*  vt     = (bf16*)take((size_t)NH * VD * S_LEN * 2);
  bf16*  ctx    = (bf16*)take((size_t)S_LEN * HID * 2);

  const dim3 tb(32, 8);
  cast_f32_bf16<<<(S_LEN * HID / 4 + 255) / 256, 256, 0, stream>>>(hidden, hid_bf, S_LEN * HID / 4);
  transpose_cast<<<dim3((QL + 31) / 32, (HID + 31) / 32), tb, 0, stream>>>(w_qa, wqaT, HID, QL);
  transpose_cast<<<dim3((QB_N + 31) / 32, (QL + 31) / 32), tb, 0, stream>>>(w_qb, wqbT, QL, QB_N);
  transpose_cast<<<dim3((CKV_N + 31) / 32, (HID + 31) / 32), tb, 0, stream>>>(w_kva, wkvaT, HID, CKV_N);
  transpose_cast<<<dim3((KVB_N + 31) / 32, (KVL + 31) / 32), tb, 0, stream>>>(w_kvb, wkvbT, KVL, KVB_N);
  transpose_cast<<<dim3((HID + 31) / 32, (HID + 31) / 32), tb, 0, stream>>>(w_o, woT, HID, HID);

  // q path
  gemm_bt<false, false><<<dim3(QL / 128, S_LEN / 128), 256, 0, stream>>>(hid_bf, wqaT, qlora, S_LEN, QL, HID);
  rmsnorm_rows<<<S_LEN, 256, 0, stream>>>(qlora, q_ln, qa_bf, QL);
  gemm_bt<true, false><<<dim3(QB_N / 128, S_LEN / 128), 256, 0, stream>>>(qa_bf, wqbT, qraw, S_LEN, QB_N, QL);
  rope_q<<<dim3(S_LEN, NH), 96, 0, stream>>>(qraw, pos, qfull);

  // kv path
  gemm_bt<false, true><<<dim3((CKV_N + 127) / 128, S_LEN / 128), 256, 0, stream>>>(hid_bf, wkvaT, ckv, S_LEN, CKV_N, HID);
  kv_prep<<<S_LEN, 64, 0, stream>>>(ckv, kv_ln, pos, ckv_bf, kpe);
  gemm_bt<true, false><<<dim3(KVB_N / 128, S_LEN / 128), 256, 0, stream>>>(ckv_bf, wkvbT, kv_bf, S_LEN, KVB_N, KVL);
  build_kfull<<<dim3(S_LEN, NH), 96, 0, stream>>>(kv_bf, kpe, kfull);
  transpose_v<<<dim3(S_LEN / 32, VD / 32, NH), tb, 0, stream>>>(kv_bf, vt);

  // attention + output proj
  attn_kernel<<<dim3(NH, S_LEN / 32), 64, 0, stream>>>(qfull, kfull, vt, ctx);
  gemm_bt<false, false><<<dim3(HID / 128, S_LEN / 128), 256, 0, stream>>>(ctx, woT, out, S_LEN, HID, HID);
}

// Round 3
// 344.050 us; speedup vs baseline: 1.4049x; 1.2356x over previous
//
#include <hip/hip_runtime.h>
#include <hip/hip_bf16.h>

typedef __hip_bfloat16 bf16;
typedef __attribute__((ext_vector_type(8))) __bf16 bf16x8;
typedef __attribute__((ext_vector_type(4))) __bf16 bf16x4;
typedef __attribute__((ext_vector_type(4))) float f32x4;

constexpr int S_LEN = 2048;
constexpr int HID   = 2560;
constexpr int NH    = 40;
constexpr int QL    = 768;
constexpr int KVL   = 256;
constexpr int RD    = 32;
constexpr int ND    = 64;
constexpr int VD    = 64;
constexpr int QHD   = 96;                 // NOPE_D + ROPE_D
constexpr int QB_N  = NH * QHD;           // 3840
constexpr int KVB_N = NH * (ND + VD);     // 5120
constexpr int CKV_N = KVL + RD;           // 288

#define MFMA16(a, b, c) __builtin_amdgcn_mfma_f32_16x16x32_bf16((a), (b), (c), 0, 0, 0)

// position_ids may arrive as int32 or int64; values are 0..2047 so sniff layout.
__device__ __forceinline__ int get_pos(const int* pos, int s) {
  bool is64 = (pos[1] == 0 && pos[2] == 1);
  return is64 ? pos[2 * s] : pos[s];
}

// ---------------- prep ----------------

__global__ void cast_f32_bf16(const float* __restrict__ src, bf16* __restrict__ dst, int n4) {
  int i = blockIdx.x * blockDim.x + threadIdx.x;
  if (i >= n4) return;
  float4 v = reinterpret_cast<const float4*>(src)[i];
  struct { bf16 a, b, c, d; } pk;
  pk.a = __float2bfloat16(v.x); pk.b = __float2bfloat16(v.y);
  pk.c = __float2bfloat16(v.z); pk.d = __float2bfloat16(v.w);
  reinterpret_cast<uint2*>(dst)[i] = *reinterpret_cast<uint2*>(&pk);
}

// src [K][N] f32 -> dst [N][K] bf16  (B^T layout for the GEMMs)
__global__ void transpose_cast(const float* __restrict__ src, bf16* __restrict__ dst, int K, int N) {
  __shared__ float tile[32][33];
  int nb = blockIdx.x * 32, kb = blockIdx.y * 32;
  int x = threadIdx.x, y = threadIdx.y; // (32,8)
#pragma unroll
  for (int j = 0; j < 4; ++j) {
    int k = kb + y + j * 8, n = nb + x;
    tile[y + j * 8][x] = (k < K && n < N) ? src[(size_t)k * N + n] : 0.f;
  }
  __syncthreads();
#pragma unroll
  for (int j = 0; j < 4; ++j) {
    int n = nb + y + j * 8, k = kb + x;
    if (n < N && k < K) dst[(size_t)n * K + k] = __float2bfloat16(tile[x][y + j * 8]);
  }
}

// ---------------- GEMM: C[M][N] = A[M][K] * B^T[N][K], bf16 in, f32 acc ----------------

template<bool OBF16, bool NEDGE>
__global__ __launch_bounds__(256) void gemm_bt(const bf16* __restrict__ A,
                                               const bf16* __restrict__ B,
                                               void* __restrict__ Cv,
                                               int M, int N, int K) {
  constexpr int BM = 128, BN = 128, BK = 64;
  __shared__ __bf16 ldsA[BM * BK];
  __shared__ __bf16 ldsB[BN * BK];
  const int t = threadIdx.x;
  const int l = t & 63, w = t >> 6;
  const int lr = l & 15, lk = l >> 4;
  const int wr = w >> 1, wc = w & 1;
  const int rowbase = blockIdx.y * BM;
  const int colbase = blockIdx.x * BN;

  f32x4 acc[4][4];
#pragma unroll
  for (int m = 0; m < 4; ++m)
#pragma unroll
    for (int n = 0; n < 4; ++n) acc[m][n] = f32x4{0.f, 0.f, 0.f, 0.f};

  const int kiters = K / BK;
  for (int kt = 0; kt < kiters; ++kt) {
    const int kb = kt * BK;
    // stage A,B tiles: linear LDS dest, inverse-swizzled global source (rule #21)
#pragma unroll
    for (int it = 0; it < 4; ++it) {
      const int r  = it * 32 + w * 8 + (l >> 3);
      const int c8 = ((l & 7) * 8) ^ ((r & 7) << 3); // element-units, 16B chunks
      const bf16* ga = A + (size_t)(rowbase + r) * K + kb + c8;
      __builtin_amdgcn_global_load_lds((const __attribute__((address_space(1))) void*)ga,
          (__attribute__((address_space(3))) void*)(ldsA + it * 2048 + w * 512), 16, 0, 0);
      int nrow = colbase + r;
      if (NEDGE) nrow = (nrow < N) ? nrow : (N - 1);
      const bf16* gb = B + (size_t)nrow * K + kb + c8;
      __builtin_amdgcn_global_load_lds((const __attribute__((address_space(1))) void*)gb,
          (__attribute__((address_space(3))) void*)(ldsB + it * 2048 + w * 512), 16, 0, 0);
    }
    __syncthreads();
#pragma unroll
    for (int kk = 0; kk < 2; ++kk) {
      bf16x8 af[4], bfr[4];
#pragma unroll
      for (int m = 0; m < 4; ++m) {
        const int row = wr * 64 + m * 16 + lr;
        const int ce  = (kk * 32 + lk * 8) ^ ((row & 7) << 3);
        af[m] = *(const bf16x8*)(ldsA + row * BK + ce);
      }
#pragma unroll
      for (int n = 0; n < 4; ++n) {
        const int row = wc * 64 + n * 16 + lr;
        const int ce  = (kk * 32 + lk * 8) ^ ((row & 7) << 3);
        bfr[n] = *(const bf16x8*)(ldsB + row * BK + ce);
      }
#pragma unroll
      for (int m = 0; m < 4; ++m)
#pragma unroll
        for (int n = 0; n < 4; ++n)
          acc[m][n] = MFMA16(af[m], bfr[n], acc[m][n]);
    }
    __syncthreads();
  }

  // epilogue: C row=(lk*4+i), col=lr within each 16x16 frag
#pragma unroll
  for (int m = 0; m < 4; ++m)
#pragma unroll
    for (int n = 0; n < 4; ++n) {
      const int col = colbase + wc * 64 + n * 16 + lr;
      if (NEDGE && col >= N) continue;
#pragma unroll
      for (int i = 0; i < 4; ++i) {
        const int row = rowbase + wr * 64 + m * 16 + lk * 4 + i;
        if (OBF16) ((bf16*)Cv)[(size_t)row * N + col] = __float2bfloat16(acc[m][n][i]);
        else       ((float*)Cv)[(size_t)row * N + col] = acc[m][n][i];
      }
    }
}

// ---------------- norms / rope / reshapes ----------------

__global__ void rmsnorm_rows(const float* __restrict__ in, const float* __restrict__ w,
                             bf16* __restrict__ out, int C) {
  const int r = blockIdx.x;
  const float* row = in + (size_t)r * C;
  float ss = 0.f;
  for (int c = threadIdx.x; c < C; c += 256) { float v = row[c]; ss += v * v; }
#pragma unroll
  for (int d = 32; d > 0; d >>= 1) ss += __shfl_xor(ss, d);
  __shared__ float red[4];
  if ((threadIdx.x & 63) == 0) red[threadIdx.x >> 6] = ss;
  __syncthreads();
  const float tot = red[0] + red[1] + red[2] + red[3];
  const float rs = rsqrtf(tot / (float)C + 1e-6f);
  for (int c = threadIdx.x; c < C; c += 256)
    out[(size_t)r * C + c] = __float2bfloat16(row[c] * rs * w[c]);
}

// per row: rmsnorm(ckv[0:256]) -> bf16 ; rope(k_pe = ckv[256:288]) -> bf16
__global__ void kv_prep(const float* __restrict__ ckv, const float* __restrict__ w,
                        const int* __restrict__ pos, bf16* __restrict__ ckv_bf,
                        bf16* __restrict__ kpe) {
  const int s = blockIdx.x, t = threadIdx.x; // 64 threads
  const float* row = ckv + (size_t)s * CKV_N;
  float v[4]; float ss = 0.f;
#pragma unroll
  for (int j = 0; j < 4; ++j) { v[j] = row[t + 64 * j]; ss += v[j] * v[j]; }
#pragma unroll
  for (int d = 32; d > 0; d >>= 1) ss += __shfl_xor(ss, d);
  const float rs = rsqrtf(ss / (float)KVL + 1e-6f);
#pragma unroll
  for (int j = 0; j < 4; ++j)
    ckv_bf[(size_t)s * KVL + t + 64 * j] = __float2bfloat16(v[j] * rs * w[t + 64 * j]);
  if (t < 16) {
    const float x0 = row[KVL + t], x1 = row[KVL + 16 + t];
    const float p = (float)get_pos(pos, s);
    const float invf = exp2f(-(float)t * (13.2877124f / 16.f)); // 10000^(-t/16)
    const float ang = p * invf, c = cosf(ang), sn = sinf(ang);
    kpe[(size_t)s * RD + t]      = __float2bfloat16(x0 * c - x1 * sn);
    kpe[(size_t)s * RD + 16 + t] = __float2bfloat16(x1 * c + x0 * sn);
  }
}

// qraw [S][3840] -> qfull [NH][S][96], rope on last 32, * (96^-0.5 * log2e)
// grid (S), block (96,4): trig computed once per thread, looped over heads.
__global__ void rope_q(const bf16* __restrict__ qraw, const int* __restrict__ pos,
                       bf16* __restrict__ qfull) {
  const int s = blockIdx.x, d = threadIdx.x; // 0..95
  const float scale = 0.14724444f;           // 96^-0.5 * log2(e)
  float c = 0.f, sn = 0.f;
  if (d >= ND) {
    const int j = (d - ND) & 15;
    const float p = (float)get_pos(pos, s);
    const float invf = exp2f(-(float)j * (13.2877124f / 16.f));
    const float ang = p * invf;
    c = cosf(ang); sn = sinf(ang);
  }
  for (int h = threadIdx.y; h < NH; h += 4) {
    const size_t src = (size_t)s * QB_N + h * QHD;
    float outv;
    if (d < ND) {
      outv = __bfloat162float(qraw[src + d]);
    } else {
      const int j = (d - ND) & 15;
      const float x0 = __bfloat162float(qraw[src + ND + j]);
      const float x1 = __bfloat162float(qraw[src + ND + 16 + j]);
      outv = (d < ND + 16) ? (x0 * c - x1 * sn) : (x1 * c + x0 * sn);
    }
    qfull[((size_t)h * S_LEN + s) * QHD + d] = __float2bfloat16(outv * scale);
  }
}

// grid (S), block (96,4)
__global__ void build_kfull(const bf16* __restrict__ kv, const bf16* __restrict__ kpe,
                            bf16* __restrict__ kfull) {
  const int s = blockIdx.x, d = threadIdx.x; // 0..95
  bf16 pe;
  if (d >= ND) pe = kpe[(size_t)s * RD + (d - ND)];
  for (int h = threadIdx.y; h < NH; h += 4) {
    bf16 v = (d < ND) ? kv[(size_t)s * KVB_N + h * (ND + VD) + d] : pe;
    kfull[((size_t)h * S_LEN + s) * QHD + d] = v;
  }
}

// V part of kv [S][5120] -> vt [NH][64][S]
__global__ void transpose_v(const bf16* __restrict__ kv, bf16* __restrict__ vt) {
  __shared__ bf16 tile[32][33];
  const int h = blockIdx.z;
  const int sb = blockIdx.x * 32, db = blockIdx.y * 32;
  const int x = threadIdx.x, y = threadIdx.y; // (32,8)
#pragma unroll
  for (int j = 0; j < 4; ++j)
    tile[y + j * 8][x] = kv[(size_t)(sb + y + j * 8) * KVB_N + h * (ND + VD) + ND + db + x];
  __syncthreads();
#pragma unroll
  for (int j = 0; j < 4; ++j)
    vt[((size_t)h * VD + db + y + j * 8) * S_LEN + sb + x] = tile[x][y + j * 8];
}

// ---------------- causal flash attention ----------------
// One wave per block, 32 q rows, KVBLK=64, K prefetch, SWAPPED QK^T:
// st = mfma(K, Q) -> S^T; lane holds 16 k-values for q = qg*16 + (lane&15),
// so row max/sum are lane-local + 2 shfl_xor. Scores arrive in log2 domain
// (log2e folded into Q), so exp2f == softmax exp.
// Grid (NH, S/32), q-tiles REVERSED (heavy first -> LPT).
__global__ __launch_bounds__(64) void attn_kernel(const bf16* __restrict__ qfull,
                                                  const bf16* __restrict__ kfull,
                                                  const bf16* __restrict__ vt,
                                                  bf16* __restrict__ ctx) {
  const int h = blockIdx.x;
  const int qw = ((int)gridDim.y - 1 - (int)blockIdx.y) * 32;
  const int l = threadIdx.x;
  const int lr = l & 15, lk = l >> 4;
  const bf16* Q  = qfull + (size_t)h * S_LEN * QHD;
  const bf16* Kf = kfull + (size_t)h * S_LEN * QHD;
  const bf16* V  = vt + (size_t)h * VD * S_LEN;
  __shared__ __bf16 plds[32][72]; // 144B row stride

  bf16x8 qf[2][3];
#pragma unroll
  for (int qg = 0; qg < 2; ++qg)
#pragma unroll
    for (int ks = 0; ks < 3; ++ks)
      qf[qg][ks] = *(const bf16x8*)(Q + (size_t)(qw + qg * 16 + lr) * QHD + ks * 32 + lk * 8);

  f32x4 o[2][4];
  float mrow[2], lrow[2];
#pragma unroll
  for (int qg = 0; qg < 2; ++qg) {
#pragma unroll
    for (int dt = 0; dt < 4; ++dt) o[qg][dt] = f32x4{0.f, 0.f, 0.f, 0.f};
    mrow[qg] = -1e30f; lrow[qg] = 0.f;
  }

  // preload K tile 0
  bf16x8 kf[4][3];
#pragma unroll
  for (int sub = 0; sub < 4; ++sub)
#pragma unroll
    for (int ks = 0; ks < 3; ++ks)
      kf[sub][ks] = *(const bf16x8*)(Kf + (size_t)(sub * 16 + lr) * QHD + ks * 32 + lk * 8);

  for (int kb = 0;; kb += 64) {
    // S^T tile: st[qg][sub][i] = S[q = qw+qg*16+lr][k = kb+sub*16+lk*4+i]
    f32x4 st[2][4];
#pragma unroll
    for (int qg = 0; qg < 2; ++qg)
#pragma unroll
      for (int sub = 0; sub < 4; ++sub) st[qg][sub] = f32x4{0.f, 0.f, 0.f, 0.f};
#pragma unroll
    for (int qg = 0; qg < 2; ++qg)
#pragma unroll
      for (int sub = 0; sub < 4; ++sub)
#pragma unroll
        for (int ks = 0; ks < 3; ++ks)
          st[qg][sub] = MFMA16(kf[sub][ks], qf[qg][ks], st[qg][sub]);

    // prefetch next K tile (hidden under softmax+PV)
    const int nkb = kb + 64;
    if (nkb <= qw) {
#pragma unroll
      for (int sub = 0; sub < 4; ++sub)
#pragma unroll
        for (int ks = 0; ks < 3; ++ks)
          kf[sub][ks] = *(const bf16x8*)(Kf + (size_t)(nkb + sub * 16 + lr) * QHD + ks * 32 + lk * 8);
    }

    const bool diag = (kb + 64 > qw);
    float fac[2];
#pragma unroll
    for (int qg = 0; qg < 2; ++qg) {
      const int q = qw + qg * 16 + lr;
      if (diag) {
#pragma unroll
        for (int sub = 0; sub < 4; ++sub)
#pragma unroll
          for (int i = 0; i < 4; ++i)
            if (kb + sub * 16 + lk * 4 + i > q) st[qg][sub][i] = -1e30f;
      }
      // row max: 16 lane-local + 2 shfl
      float tm = -1e30f;
#pragma unroll
      for (int sub = 0; sub < 4; ++sub)
#pragma unroll
        for (int i = 0; i < 4; ++i) tm = fmaxf(tm, st[qg][sub][i]);
      tm = fmaxf(tm, __shfl_xor(tm, 16));
      tm = fmaxf(tm, __shfl_xor(tm, 32));
      const float mnew = fmaxf(mrow[qg], tm);
      fac[qg] = exp2f(mrow[qg] - mnew);
      mrow[qg] = mnew;
      float ts = 0.f;
#pragma unroll
      for (int sub = 0; sub < 4; ++sub) {
        bf16x4 pk;
#pragma unroll
        for (int i = 0; i < 4; ++i) {
          const float p = exp2f(st[qg][sub][i] - mnew);
          ts += p;
          pk[i] = (__bf16)p;
        }
        *(bf16x4*)(&plds[qg * 16 + lr][sub * 16 + lk * 4]) = pk;
      }
      ts += __shfl_xor(ts, 16);
      ts += __shfl_xor(ts, 32);
      lrow[qg] = lrow[qg] * fac[qg] + ts;
    }
    // rescale o: factor for o-row (lk*4+i) fetched from lane (lk*4+i)
#pragma unroll
    for (int qg = 0; qg < 2; ++qg)
#pragma unroll
      for (int i = 0; i < 4; ++i) {
        const float fr = __shfl(fac[qg], lk * 4 + i);
#pragma unroll
        for (int dt = 0; dt < 4; ++dt) o[qg][dt][i] *= fr;
      }

    // PV: A = P from LDS (A-frag layout), B = V^T rows (contiguous in s)
#pragma unroll
    for (int h2 = 0; h2 < 2; ++h2) {
      bf16x8 pa0 = *(const bf16x8*)(&plds[lr][h2 * 32 + lk * 8]);
      bf16x8 pa1 = *(const bf16x8*)(&plds[16 + lr][h2 * 32 + lk * 8]);
#pragma unroll
      for (int dt = 0; dt < 4; ++dt) {
        bf16x8 vf = *(const bf16x8*)(V + (size_t)(dt * 16 + lr) * S_LEN + kb + h2 * 32 + lk * 8);
        o[0][dt] = MFMA16(pa0, vf, o[0][dt]);
        o[1][dt] = MFMA16(pa1, vf, o[1][dt]);
      }
    }
    if (nkb > qw) break;
  }

#pragma unroll
  for (int qg = 0; qg < 2; ++qg) {
    const float linv = 1.0f / lrow[qg];
#pragma unroll
    for (int i = 0; i < 4; ++i) {
      const float inv = __shfl(linv, lk * 4 + i);
#pragma unroll
      for (int dt = 0; dt < 4; ++dt) {
        const int row = qw + qg * 16 + lk * 4 + i;
        const int col = h * VD + dt * 16 + lr;
        ctx[(size_t)row * HID + col] = __float2bfloat16(o[qg][dt][i] * inv);
      }
    }
  }
}

// ---------------- launch ----------------

extern "C" void kernel_launch(void* const* d_in, const int* in_sizes, int n_in,
                              void* d_out, int out_size, void* d_ws, size_t ws_size,
                              hipStream_t stream) {
  const float* hidden = (const float*)d_in[0];
  const int*   pos    = (const int*)d_in[1];
  const float* w_qa   = (const float*)d_in[2];
  const float* q_ln   = (const float*)d_in[3];
  const float* w_qb   = (const float*)d_in[4];
  const float* w_kva  = (const float*)d_in[5];
  const float* kv_ln  = (const float*)d_in[6];
  const float* w_kvb  = (const float*)d_in[7];
  const float* w_o    = (const float*)d_in[8];
  float* out = (float*)d_out;
  char* ws = (char*)d_ws;
  (void)in_sizes; (void)n_in; (void)out_size; (void)ws_size;

  size_t off = 0;
  auto take = [&](size_t bytes) -> char* {
    char* p = ws + off;
    off = (off + bytes + 255) & ~(size_t)255;
    return p;
  };
  bf16*  hid_bf = (bf16*)take((size_t)S_LEN * HID * 2);
  bf16*  wqaT   = (bf16*)take((size_t)QL * HID * 2);
  bf16*  wqbT   = (bf16*)take((size_t)QB_N * QL * 2);
  bf16*  wkvaT  = (bf16*)take((size_t)CKV_N * HID * 2);
  bf16*  wkvbT  = (bf16*)take((size_t)KVB_N * KVL * 2);
  bf16*  woT    = (bf16*)take((size_t)HID * HID * 2);
  float* qlora  = (float*)take((size_t)S_LEN * QL * 4);
  bf16*  qa_bf  = (bf16*)take((size_t)S_LEN * QL * 2);
  bf16*  qraw   = (bf16*)take((size_t)S_LEN * QB_N * 2);
  bf16*  qfull  = (bf16*)take((size_t)NH * S_LEN * QHD * 2);
  float* ckv    = (float*)take((size_t)S_LEN * CKV_N * 4);
  bf16*  ckv_bf = (bf16*)take((size_t)S_LEN * KVL * 2);
  bf16*  kpe    = (bf16*)take((size_t)S_LEN * RD * 2);
  bf16*  kv_bf  = (bf16*)take((size_t)S_LEN * KVB_N * 2);
  bf16*  kfull  = (bf16*)take((size_t)NH * S_LEN * QHD * 2);
  bf16*  vt     = (bf16*)take((size_t)NH * VD * S_LEN * 2);
  bf16*  ctx    = (bf16*)take((size_t)S_LEN * HID * 2);

  const dim3 tb(32, 8);
  cast_f32_bf16<<<(S_LEN * HID / 4 + 255) / 256, 256, 0, stream>>>(hidden, hid_bf, S_LEN * HID / 4);
  transpose_cast<<<dim3((QL + 31) / 32, (HID + 31) / 32), tb, 0, stream>>>(w_qa, wqaT, HID, QL);
  transpose_cast<<<dim3((QB_N + 31) / 32, (QL + 31) / 32), tb, 0, stream>>>(w_qb, wqbT, QL, QB_N);
  transpose_cast<<<dim3((CKV_N + 31) / 32, (HID + 31) / 32), tb, 0, stream>>>(w_kva, wkvaT, HID, CKV_N);
  transpose_cast<<<dim3((KVB_N + 31) / 32, (KVL + 31) / 32), tb, 0, stream>>>(w_kvb, wkvbT, KVL, KVB_N);
  transpose_cast<<<dim3((HID + 31) / 32, (HID + 31) / 32), tb, 0, stream>>>(w_o, woT, HID, HID);

  // q path
  gemm_bt<false, false><<<dim3(QL / 128, S_LEN / 128), 256, 0, stream>>>(hid_bf, wqaT, qlora, S_LEN, QL, HID);
  rmsnorm_rows<<<S_LEN, 256, 0, stream>>>(qlora, q_ln, qa_bf, QL);
  gemm_bt<true, false><<<dim3(QB_N / 128, S_LEN / 128), 256, 0, stream>>>(qa_bf, wqbT, qraw, S_LEN, QB_N, QL);
  rope_q<<<S_LEN, dim3(96, 4), 0, stream>>>(qraw, pos, qfull);

  // kv path
  gemm_bt<false, true><<<dim3((CKV_N + 127) / 128, S_LEN / 128), 256, 0, stream>>>(hid_bf, wkvaT, ckv, S_LEN, CKV_N, HID);
  kv_prep<<<S_LEN, 64, 0, stream>>>(ckv, kv_ln, pos, ckv_bf, kpe);
  gemm_bt<true, false><<<dim3(KVB_N / 128, S_LEN / 128), 256, 0, stream>>>(ckv_bf, wkvbT, kv_bf, S_LEN, KVB_N, KVL);
  build_kfull<<<S_LEN, dim3(96, 4), 0, stream>>>(kv_bf, kpe, kfull);
  transpose_v<<<dim3(S_LEN / 32, VD / 32, NH), tb, 0, stream>>>(kv_bf, vt);

  // attention + output proj
  attn_kernel<<<dim3(NH, S_LEN / 32), 64, 0, stream>>>(qfull, kfull, vt, ctx);
  gemm_bt<false, false><<<dim3(HID / 128, S_LEN / 128), 256, 0, stream>>>(ctx, woT, out, S_LEN, HID, HID);
}

// Round 4
// 285.960 us; speedup vs baseline: 1.6903x; 1.2031x over previous
//
#include <hip/hip_runtime.h>
#include <hip/hip_bf16.h>

typedef __hip_bfloat16 bf16;
typedef __attribute__((ext_vector_type(8))) __bf16 bf16x8;
typedef __attribute__((ext_vector_type(4))) __bf16 bf16x4;
typedef __attribute__((ext_vector_type(4))) float f32x4;

constexpr int S_LEN = 2048;
constexpr int HID   = 2560;
constexpr int NH    = 40;
constexpr int QL    = 768;
constexpr int KVL   = 256;
constexpr int RD    = 32;
constexpr int ND    = 64;
constexpr int VD    = 64;
constexpr int QHD   = 96;                 // NOPE_D + ROPE_D
constexpr int QB_N  = NH * QHD;           // 3840
constexpr int KVB_N = NH * (ND + VD);     // 5120
constexpr int CKV_N = KVL + RD;           // 288
constexpr int AB_N  = QL + CKV_N;         // 1056 (fused qa|kva output cols)

#define MFMA16(a, b, c) __builtin_amdgcn_mfma_f32_16x16x32_bf16((a), (b), (c), 0, 0, 0)

// position_ids may arrive as int32 or int64; values are 0..2047 so sniff layout.
__device__ __forceinline__ int get_pos(const int* pos, int s) {
  bool is64 = (pos[1] == 0 && pos[2] == 1);
  return is64 ? pos[2 * s] : pos[s];
}

// ---------------- prep ----------------

__global__ void cast_f32_bf16(const float* __restrict__ src, bf16* __restrict__ dst, int n4) {
  int i = blockIdx.x * blockDim.x + threadIdx.x;
  if (i >= n4) return;
  float4 v = reinterpret_cast<const float4*>(src)[i];
  struct { bf16 a, b, c, d; } pk;
  pk.a = __float2bfloat16(v.x); pk.b = __float2bfloat16(v.y);
  pk.c = __float2bfloat16(v.z); pk.d = __float2bfloat16(v.w);
  reinterpret_cast<uint2*>(dst)[i] = *reinterpret_cast<uint2*>(&pk);
}

// src [K][N] f32 -> dst [N][K] bf16  (B^T layout for the GEMMs)
__global__ void transpose_cast(const float* __restrict__ src, bf16* __restrict__ dst, int K, int N) {
  __shared__ float tile[32][33];
  int nb = blockIdx.x * 32, kb = blockIdx.y * 32;
  int x = threadIdx.x, y = threadIdx.y; // (32,8)
#pragma unroll
  for (int j = 0; j < 4; ++j) {
    int k = kb + y + j * 8, n = nb + x;
    tile[y + j * 8][x] = (k < K && n < N) ? src[(size_t)k * N + n] : 0.f;
  }
  __syncthreads();
#pragma unroll
  for (int j = 0; j < 4; ++j) {
    int n = nb + y + j * 8, k = kb + x;
    if (n < N && k < K) dst[(size_t)n * K + k] = __float2bfloat16(tile[x][y + j * 8]);
  }
}

// ---------------- GEMM: C[M][N] = A[M][K] * B^T[N][K], bf16 in, f32 acc ----------------

template<bool OBF16, bool NEDGE>
__global__ __launch_bounds__(256) void gemm_bt(const bf16* __restrict__ A,
                                               const bf16* __restrict__ B,
                                               void* __restrict__ Cv,
                                               int M, int N, int K) {
  constexpr int BM = 128, BN = 128, BK = 64;
  __shared__ __bf16 ldsA[BM * BK];
  __shared__ __bf16 ldsB[BN * BK];
  const int t = threadIdx.x;
  const int l = t & 63, w = t >> 6;
  const int lr = l & 15, lk = l >> 4;
  const int wr = w >> 1, wc = w & 1;
  const int rowbase = blockIdx.y * BM;
  const int colbase = blockIdx.x * BN;

  f32x4 acc[4][4];
#pragma unroll
  for (int m = 0; m < 4; ++m)
#pragma unroll
    for (int n = 0; n < 4; ++n) acc[m][n] = f32x4{0.f, 0.f, 0.f, 0.f};

  const int kiters = K / BK;
  for (int kt = 0; kt < kiters; ++kt) {
    const int kb = kt * BK;
    // stage A,B tiles: linear LDS dest, inverse-swizzled global source (rule #21)
#pragma unroll
    for (int it = 0; it < 4; ++it) {
      const int r  = it * 32 + w * 8 + (l >> 3);
      const int c8 = ((l & 7) * 8) ^ ((r & 7) << 3); // element-units, 16B chunks
      const bf16* ga = A + (size_t)(rowbase + r) * K + kb + c8;
      __builtin_amdgcn_global_load_lds((const __attribute__((address_space(1))) void*)ga,
          (__attribute__((address_space(3))) void*)(ldsA + it * 2048 + w * 512), 16, 0, 0);
      int nrow = colbase + r;
      if (NEDGE) nrow = (nrow < N) ? nrow : (N - 1);
      const bf16* gb = B + (size_t)nrow * K + kb + c8;
      __builtin_amdgcn_global_load_lds((const __attribute__((address_space(1))) void*)gb,
          (__attribute__((address_space(3))) void*)(ldsB + it * 2048 + w * 512), 16, 0, 0);
    }
    __syncthreads();
#pragma unroll
    for (int kk = 0; kk < 2; ++kk) {
      bf16x8 af[4], bfr[4];
#pragma unroll
      for (int m = 0; m < 4; ++m) {
        const int row = wr * 64 + m * 16 + lr;
        const int ce  = (kk * 32 + lk * 8) ^ ((row & 7) << 3);
        af[m] = *(const bf16x8*)(ldsA + row * BK + ce);
      }
#pragma unroll
      for (int n = 0; n < 4; ++n) {
        const int row = wc * 64 + n * 16 + lr;
        const int ce  = (kk * 32 + lk * 8) ^ ((row & 7) << 3);
        bfr[n] = *(const bf16x8*)(ldsB + row * BK + ce);
      }
#pragma unroll
      for (int m = 0; m < 4; ++m)
#pragma unroll
        for (int n = 0; n < 4; ++n)
          acc[m][n] = MFMA16(af[m], bfr[n], acc[m][n]);
    }
    __syncthreads();
  }

  // epilogue: C row=(lk*4+i), col=lr within each 16x16 frag
#pragma unroll
  for (int m = 0; m < 4; ++m)
#pragma unroll
    for (int n = 0; n < 4; ++n) {
      const int col = colbase + wc * 64 + n * 16 + lr;
      if (NEDGE && col >= N) continue;
#pragma unroll
      for (int i = 0; i < 4; ++i) {
        const int row = rowbase + wr * 64 + m * 16 + lk * 4 + i;
        if (OBF16) ((bf16*)Cv)[(size_t)row * N + col] = __float2bfloat16(acc[m][n][i]);
        else       ((float*)Cv)[(size_t)row * N + col] = acc[m][n][i];
      }
    }
}

// Fused qa|kva GEMM: C[2048][1056] = hid_bf * wabT^T, BN=64 tiles (4 waves
// stacked in M, 32 rows x 64 cols each) for occupancy on the skinny N.
// cols 0..767 -> q_out (stride 768), cols 768..1055 -> ckv_out (stride 288).
__global__ __launch_bounds__(256) void gemm_qakva(const bf16* __restrict__ A,
                                                  const bf16* __restrict__ B,
                                                  float* __restrict__ q_out,
                                                  float* __restrict__ ckv_out) {
  constexpr int BM = 128, BK = 64, K = HID, N = AB_N;
  __shared__ __bf16 ldsA[BM * BK]; // 16KB
  __shared__ __bf16 ldsB[64 * BK]; // 8KB
  const int t = threadIdx.x;
  const int l = t & 63, w = t >> 6;
  const int lr = l & 15, lk = l >> 4;
  const int rowbase = blockIdx.y * BM;
  const int colbase = blockIdx.x * 64;

  f32x4 acc[2][4];
#pragma unroll
  for (int m = 0; m < 2; ++m)
#pragma unroll
    for (int n = 0; n < 4; ++n) acc[m][n] = f32x4{0.f, 0.f, 0.f, 0.f};

  for (int kt = 0; kt < K / BK; ++kt) {
    const int kb = kt * BK;
#pragma unroll
    for (int it = 0; it < 4; ++it) {
      const int r  = it * 32 + w * 8 + (l >> 3);
      const int c8 = ((l & 7) * 8) ^ ((r & 7) << 3);
      const bf16* ga = A + (size_t)(rowbase + r) * K + kb + c8;
      __builtin_amdgcn_global_load_lds((const __attribute__((address_space(1))) void*)ga,
          (__attribute__((address_space(3))) void*)(ldsA + it * 2048 + w * 512), 16, 0, 0);
      if (it < 2) {
        int nrow = colbase + r;
        nrow = (nrow < N) ? nrow : (N - 1);
        const bf16* gb = B + (size_t)nrow * K + kb + c8;
        __builtin_amdgcn_global_load_lds((const __attribute__((address_space(1))) void*)gb,
            (__attribute__((address_space(3))) void*)(ldsB + it * 2048 + w * 512), 16, 0, 0);
      }
    }
    __syncthreads();
#pragma unroll
    for (int kk = 0; kk < 2; ++kk) {
      bf16x8 af[2], bfr[4];
#pragma unroll
      for (int m = 0; m < 2; ++m) {
        const int row = w * 32 + m * 16 + lr;
        const int ce  = (kk * 32 + lk * 8) ^ ((row & 7) << 3);
        af[m] = *(const bf16x8*)(ldsA + row * BK + ce);
      }
#pragma unroll
      for (int n = 0; n < 4; ++n) {
        const int row = n * 16 + lr;
        const int ce  = (kk * 32 + lk * 8) ^ ((row & 7) << 3);
        bfr[n] = *(const bf16x8*)(ldsB + row * BK + ce);
      }
#pragma unroll
      for (int m = 0; m < 2; ++m)
#pragma unroll
        for (int n = 0; n < 4; ++n)
          acc[m][n] = MFMA16(af[m], bfr[n], acc[m][n]);
    }
    __syncthreads();
  }

#pragma unroll
  for (int m = 0; m < 2; ++m)
#pragma unroll
    for (int n = 0; n < 4; ++n) {
      const int col = colbase + n * 16 + lr;
#pragma unroll
      for (int i = 0; i < 4; ++i) {
        const int row = rowbase + w * 32 + m * 16 + lk * 4 + i;
        if (col < QL)       q_out[(size_t)row * QL + col] = acc[m][n][i];
        else if (col < N)   ckv_out[(size_t)row * CKV_N + (col - QL)] = acc[m][n][i];
      }
    }
}

// ---------------- norms / rope / reshapes ----------------

__global__ void rmsnorm_rows(const float* __restrict__ in, const float* __restrict__ w,
                             bf16* __restrict__ out, int C) {
  const int r = blockIdx.x;
  const float* row = in + (size_t)r * C;
  float ss = 0.f;
  for (int c = threadIdx.x; c < C; c += 256) { float v = row[c]; ss += v * v; }
#pragma unroll
  for (int d = 32; d > 0; d >>= 1) ss += __shfl_xor(ss, d);
  __shared__ float red[4];
  if ((threadIdx.x & 63) == 0) red[threadIdx.x >> 6] = ss;
  __syncthreads();
  const float tot = red[0] + red[1] + red[2] + red[3];
  const float rs = rsqrtf(tot / (float)C + 1e-6f);
  for (int c = threadIdx.x; c < C; c += 256)
    out[(size_t)r * C + c] = __float2bfloat16(row[c] * rs * w[c]);
}

// per row: rmsnorm(ckv[0:256]) -> bf16 ; rope(k_pe = ckv[256:288]) -> bf16
__global__ void kv_prep(const float* __restrict__ ckv, const float* __restrict__ w,
                        const int* __restrict__ pos, bf16* __restrict__ ckv_bf,
                        bf16* __restrict__ kpe) {
  const int s = blockIdx.x, t = threadIdx.x; // 64 threads
  const float* row = ckv + (size_t)s * CKV_N;
  float v[4]; float ss = 0.f;
#pragma unroll
  for (int j = 0; j < 4; ++j) { v[j] = row[t + 64 * j]; ss += v[j] * v[j]; }
#pragma unroll
  for (int d = 32; d > 0; d >>= 1) ss += __shfl_xor(ss, d);
  const float rs = rsqrtf(ss / (float)KVL + 1e-6f);
#pragma unroll
  for (int j = 0; j < 4; ++j)
    ckv_bf[(size_t)s * KVL + t + 64 * j] = __float2bfloat16(v[j] * rs * w[t + 64 * j]);
  if (t < 16) {
    const float x0 = row[KVL + t], x1 = row[KVL + 16 + t];
    const float p = (float)get_pos(pos, s);
    const float invf = exp2f(-(float)t * (13.2877124f / 16.f)); // 10000^(-t/16)
    const float ang = p * invf, c = cosf(ang), sn = sinf(ang);
    kpe[(size_t)s * RD + t]      = __float2bfloat16(x0 * c - x1 * sn);
    kpe[(size_t)s * RD + 16 + t] = __float2bfloat16(x1 * c + x0 * sn);
  }
}

// qraw [S][3840] -> qfull [NH][S][96], rope on last 32, * (96^-0.5 * log2e)
// grid (S), block (96,4): trig computed once per thread, looped over heads.
__global__ void rope_q(const bf16* __restrict__ qraw, const int* __restrict__ pos,
                       bf16* __restrict__ qfull) {
  const int s = blockIdx.x, d = threadIdx.x; // 0..95
  const float scale = 0.14724444f;           // 96^-0.5 * log2(e)
  float c = 0.f, sn = 0.f;
  if (d >= ND) {
    const int j = (d - ND) & 15;
    const float p = (float)get_pos(pos, s);
    const float invf = exp2f(-(float)j * (13.2877124f / 16.f));
    const float ang = p * invf;
    c = cosf(ang); sn = sinf(ang);
  }
  for (int h = threadIdx.y; h < NH; h += 4) {
    const size_t src = (size_t)s * QB_N + h * QHD;
    float outv;
    if (d < ND) {
      outv = __bfloat162float(qraw[src + d]);
    } else {
      const int j = (d - ND) & 15;
      const float x0 = __bfloat162float(qraw[src + ND + j]);
      const float x1 = __bfloat162float(qraw[src + ND + 16 + j]);
      outv = (d < ND + 16) ? (x0 * c - x1 * sn) : (x1 * c + x0 * sn);
    }
    qfull[((size_t)h * S_LEN + s) * QHD + d] = __float2bfloat16(outv * scale);
  }
}

// grid (S), block (96,4)
__global__ void build_kfull(const bf16* __restrict__ kv, const bf16* __restrict__ kpe,
                            bf16* __restrict__ kfull) {
  const int s = blockIdx.x, d = threadIdx.x; // 0..95
  bf16 pe;
  if (d >= ND) pe = kpe[(size_t)s * RD + (d - ND)];
  for (int h = threadIdx.y; h < NH; h += 4) {
    bf16 v = (d < ND) ? kv[(size_t)s * KVB_N + h * (ND + VD) + d] : pe;
    kfull[((size_t)h * S_LEN + s) * QHD + d] = v;
  }
}

// V part of kv [S][5120] -> vt [NH][64][S]
__global__ void transpose_v(const bf16* __restrict__ kv, bf16* __restrict__ vt) {
  __shared__ bf16 tile[32][33];
  const int h = blockIdx.z;
  const int sb = blockIdx.x * 32, db = blockIdx.y * 32;
  const int x = threadIdx.x, y = threadIdx.y; // (32,8)
#pragma unroll
  for (int j = 0; j < 4; ++j)
    tile[y + j * 8][x] = kv[(size_t)(sb + y + j * 8) * KVB_N + h * (ND + VD) + ND + db + x];
  __syncthreads();
#pragma unroll
  for (int j = 0; j < 4; ++j)
    vt[((size_t)h * VD + db + y + j * 8) * S_LEN + sb + x] = tile[x][y + j * 8];
}

// ---------------- causal flash attention ----------------
// One wave per block, 32 q rows, KVBLK=64, K prefetch, SWAPPED QK^T
// (st = mfma(K,Q) -> S^T, row-reduce = lane-local + 2 shfl), log2-domain
// softmax (log2e folded into Q scale), defer-rescale (skip O-rescale while
// tile max stays within 8 of running max; P bounded by 2^8), XOR-swizzled
// P tile in LDS. Grid (NH, S/32), q-tiles REVERSED (heavy first -> LPT).
__global__ __launch_bounds__(64) void attn_kernel(const bf16* __restrict__ qfull,
                                                  const bf16* __restrict__ kfull,
                                                  const bf16* __restrict__ vt,
                                                  bf16* __restrict__ ctx) {
  const int h = blockIdx.x;
  const int qw = ((int)gridDim.y - 1 - (int)blockIdx.y) * 32;
  const int l = threadIdx.x;
  const int lr = l & 15, lk = l >> 4;
  const bf16* Q  = qfull + (size_t)h * S_LEN * QHD;
  const bf16* Kf = kfull + (size_t)h * S_LEN * QHD;
  const bf16* V  = vt + (size_t)h * VD * S_LEN;
  __shared__ __bf16 plds[32][64]; // XOR-swizzled: col ^= (row&7)<<3

  bf16x8 qf[2][3];
#pragma unroll
  for (int qg = 0; qg < 2; ++qg)
#pragma unroll
    for (int ks = 0; ks < 3; ++ks)
      qf[qg][ks] = *(const bf16x8*)(Q + (size_t)(qw + qg * 16 + lr) * QHD + ks * 32 + lk * 8);

  f32x4 o[2][4];
  float mrow[2], lrow[2];
#pragma unroll
  for (int qg = 0; qg < 2; ++qg) {
#pragma unroll
    for (int dt = 0; dt < 4; ++dt) o[qg][dt] = f32x4{0.f, 0.f, 0.f, 0.f};
    mrow[qg] = -1e30f; lrow[qg] = 0.f;
  }

  // preload K tile 0
  bf16x8 kf[4][3];
#pragma unroll
  for (int sub = 0; sub < 4; ++sub)
#pragma unroll
    for (int ks = 0; ks < 3; ++ks)
      kf[sub][ks] = *(const bf16x8*)(Kf + (size_t)(sub * 16 + lr) * QHD + ks * 32 + lk * 8);

  for (int kb = 0;; kb += 64) {
    // S^T tile: st[qg][sub][i] = S[q = qw+qg*16+lr][k = kb+sub*16+lk*4+i]
    f32x4 st[2][4];
#pragma unroll
    for (int qg = 0; qg < 2; ++qg)
#pragma unroll
      for (int sub = 0; sub < 4; ++sub) st[qg][sub] = f32x4{0.f, 0.f, 0.f, 0.f};
#pragma unroll
    for (int qg = 0; qg < 2; ++qg)
#pragma unroll
      for (int sub = 0; sub < 4; ++sub)
#pragma unroll
        for (int ks = 0; ks < 3; ++ks)
          st[qg][sub] = MFMA16(kf[sub][ks], qf[qg][ks], st[qg][sub]);

    // prefetch next K tile (hidden under softmax+PV)
    const int nkb = kb + 64;
    if (nkb <= qw) {
#pragma unroll
      for (int sub = 0; sub < 4; ++sub)
#pragma unroll
        for (int ks = 0; ks < 3; ++ks)
          kf[sub][ks] = *(const bf16x8*)(Kf + (size_t)(nkb + sub * 16 + lr) * QHD + ks * 32 + lk * 8);
    }

    const bool diag = (kb + 64 > qw);
    float tm[2];
#pragma unroll
    for (int qg = 0; qg < 2; ++qg) {
      const int q = qw + qg * 16 + lr;
      if (diag) {
#pragma unroll
        for (int sub = 0; sub < 4; ++sub)
#pragma unroll
          for (int i = 0; i < 4; ++i)
            if (kb + sub * 16 + lk * 4 + i > q) st[qg][sub][i] = -1e30f;
      }
      float m0 = -1e30f;
#pragma unroll
      for (int sub = 0; sub < 4; ++sub)
#pragma unroll
        for (int i = 0; i < 4; ++i) m0 = fmaxf(m0, st[qg][sub][i]);
      m0 = fmaxf(m0, __shfl_xor(m0, 16));
      m0 = fmaxf(m0, __shfl_xor(m0, 32));
      tm[qg] = m0;
    }

    // defer-rescale: if no row grew past m+8, keep old max (P <= 2^8).
    const bool noresc = __all((tm[0] <= mrow[0] + 8.f) && (tm[1] <= mrow[1] + 8.f));
    float fac[2];
#pragma unroll
    for (int qg = 0; qg < 2; ++qg) {
      const float mnew = noresc ? mrow[qg] : fmaxf(mrow[qg], tm[qg]);
      float ts = 0.f;
#pragma unroll
      for (int sub = 0; sub < 4; ++sub) {
        bf16x4 pk;
#pragma unroll
        for (int i = 0; i < 4; ++i) {
          const float p = exp2f(st[qg][sub][i] - mnew);
          ts += p;
          pk[i] = (__bf16)p;
        }
        const int swc = (sub * 16 + lk * 4) ^ ((lr & 7) << 3);
        *(bf16x4*)(&plds[qg * 16 + lr][swc]) = pk;
      }
      ts += __shfl_xor(ts, 16);
      ts += __shfl_xor(ts, 32);
      if (noresc) {
        lrow[qg] += ts;
      } else {
        fac[qg] = exp2f(mrow[qg] - mnew);
        lrow[qg] = lrow[qg] * fac[qg] + ts;
        mrow[qg] = mnew;
      }
    }
    if (!noresc) {
#pragma unroll
      for (int qg = 0; qg < 2; ++qg)
#pragma unroll
        for (int i = 0; i < 4; ++i) {
          const float fr = __shfl(fac[qg], lk * 4 + i);
#pragma unroll
          for (int dt = 0; dt < 4; ++dt) o[qg][dt][i] *= fr;
        }
    }

    // PV: A = P from LDS (A-frag layout, swizzled read), B = V^T rows
#pragma unroll
    for (int h2 = 0; h2 < 2; ++h2) {
      const int swc = (h2 * 32 + lk * 8) ^ ((lr & 7) << 3);
      bf16x8 pa0 = *(const bf16x8*)(&plds[lr][swc]);
      bf16x8 pa1 = *(const bf16x8*)(&plds[16 + lr][swc]);
#pragma unroll
      for (int dt = 0; dt < 4; ++dt) {
        bf16x8 vf = *(const bf16x8*)(V + (size_t)(dt * 16 + lr) * S_LEN + kb + h2 * 32 + lk * 8);
        o[0][dt] = MFMA16(pa0, vf, o[0][dt]);
        o[1][dt] = MFMA16(pa1, vf, o[1][dt]);
      }
    }
    if (nkb > qw) break;
  }

#pragma unroll
  for (int qg = 0; qg < 2; ++qg) {
    const float linv = 1.0f / lrow[qg];
#pragma unroll
    for (int i = 0; i < 4; ++i) {
      const float inv = __shfl(linv, lk * 4 + i);
#pragma unroll
      for (int dt = 0; dt < 4; ++dt) {
        const int row = qw + qg * 16 + lk * 4 + i;
        const int col = h * VD + dt * 16 + lr;
        ctx[(size_t)row * HID + col] = __float2bfloat16(o[qg][dt][i] * inv);
      }
    }
  }
}

// ---------------- launch ----------------

extern "C" void kernel_launch(void* const* d_in, const int* in_sizes, int n_in,
                              void* d_out, int out_size, void* d_ws, size_t ws_size,
                              hipStream_t stream) {
  const float* hidden = (const float*)d_in[0];
  const int*   pos    = (const int*)d_in[1];
  const float* w_qa   = (const float*)d_in[2];
  const float* q_ln   = (const float*)d_in[3];
  const float* w_qb   = (const float*)d_in[4];
  const float* w_kva  = (const float*)d_in[5];
  const float* kv_ln  = (const float*)d_in[6];
  const float* w_kvb  = (const float*)d_in[7];
  const float* w_o    = (const float*)d_in[8];
  float* out = (float*)d_out;
  char* ws = (char*)d_ws;
  (void)in_sizes; (void)n_in; (void)out_size; (void)ws_size;

  size_t off = 0;
  auto take = [&](size_t bytes) -> char* {
    char* p = ws + off;
    off = (off + bytes + 255) & ~(size_t)255;
    return p;
  };
  bf16*  hid_bf = (bf16*)take((size_t)S_LEN * HID * 2);
  bf16*  wabT   = (bf16*)take((size_t)AB_N * HID * 2);   // [1056][2560]: wqaT | wkvaT
  bf16*  wqbT   = (bf16*)take((size_t)QB_N * QL * 2);
  bf16*  wkvbT  = (bf16*)take((size_t)KVB_N * KVL * 2);
  bf16*  woT    = (bf16*)take((size_t)HID * HID * 2);
  float* qlora  = (float*)take((size_t)S_LEN * QL * 4);
  bf16*  qa_bf  = (bf16*)take((size_t)S_LEN * QL * 2);
  bf16*  qraw   = (bf16*)take((size_t)S_LEN * QB_N * 2);
  bf16*  qfull  = (bf16*)take((size_t)NH * S_LEN * QHD * 2);
  float* ckv    = (float*)take((size_t)S_LEN * CKV_N * 4);
  bf16*  ckv_bf = (bf16*)take((size_t)S_LEN * KVL * 2);
  bf16*  kpe    = (bf16*)take((size_t)S_LEN * RD * 2);
  bf16*  kv_bf  = (bf16*)take((size_t)S_LEN * KVB_N * 2);
  bf16*  kfull  = (bf16*)take((size_t)NH * S_LEN * QHD * 2);
  bf16*  vt     = (bf16*)take((size_t)NH * VD * S_LEN * 2);
  bf16*  ctx    = (bf16*)take((size_t)S_LEN * HID * 2);

  const dim3 tb(32, 8);
  cast_f32_bf16<<<(S_LEN * HID / 4 + 255) / 256, 256, 0, stream>>>(hidden, hid_bf, S_LEN * HID / 4);
  transpose_cast<<<dim3((QL + 31) / 32, (HID + 31) / 32), tb, 0, stream>>>(w_qa, wabT, HID, QL);
  transpose_cast<<<dim3((CKV_N + 31) / 32, (HID + 31) / 32), tb, 0, stream>>>(w_kva, wabT + (size_t)QL * HID, HID, CKV_N);
  transpose_cast<<<dim3((QB_N + 31) / 32, (QL + 31) / 32), tb, 0, stream>>>(w_qb, wqbT, QL, QB_N);
  transpose_cast<<<dim3((KVB_N + 31) / 32, (KVL + 31) / 32), tb, 0, stream>>>(w_kvb, wkvbT, KVL, KVB_N);
  transpose_cast<<<dim3((HID + 31) / 32, (HID + 31) / 32), tb, 0, stream>>>(w_o, woT, HID, HID);

  // fused qa|kva GEMM (272 blocks)
  gemm_qakva<<<dim3((AB_N + 63) / 64, S_LEN / 128), 256, 0, stream>>>(hid_bf, wabT, qlora, ckv);

  // q path
  rmsnorm_rows<<<S_LEN, 256, 0, stream>>>(qlora, q_ln, qa_bf, QL);
  gemm_bt<true, false><<<dim3(QB_N / 128, S_LEN / 128), 256, 0, stream>>>(qa_bf, wqbT, qraw, S_LEN, QB_N, QL);
  rope_q<<<S_LEN, dim3(96, 4), 0, stream>>>(qraw, pos, qfull);

  // kv path
  kv_prep<<<S_LEN, 64, 0, stream>>>(ckv, kv_ln, pos, ckv_bf, kpe);
  gemm_bt<true, false><<<dim3(KVB_N / 128, S_LEN / 128), 256, 0, stream>>>(ckv_bf, wkvbT, kv_bf, S_LEN, KVB_N, KVL);
  build_kfull<<<S_LEN, dim3(96, 4), 0, stream>>>(kv_bf, kpe, kfull);
  transpose_v<<<dim3(S_LEN / 32, VD / 32, NH), tb, 0, stream>>>(kv_bf, vt);

  // attention + output proj
  attn_kernel<<<dim3(NH, S_LEN / 32), 64, 0, stream>>>(qfull, kfull, vt, ctx);
  gemm_bt<false, false><<<dim3(HID / 128, S_LEN / 128), 256, 0, stream>>>(ctx, woT, out, S_LEN, HID, HID);
}